// Round 1
// baseline (630.372 us; speedup 1.0000x reference)
//
#include <hip/hip_runtime.h>

#define B_ 256
#define T_ 256
#define D_ 128
#define H_ 256

typedef _Float16 f16;
typedef f16 f16x2 __attribute__((ext_vector_type(2)));
typedef short bf16x8 __attribute__((ext_vector_type(8)));
typedef float f32x4 __attribute__((ext_vector_type(4)));

__device__ __forceinline__ unsigned short f2bf(float f) {
  union { float f; unsigned u; } c; c.f = f;
  unsigned r = c.u + 0x7fffu + ((c.u >> 16) & 1u);
  return (unsigned short)(r >> 16);
}
__device__ __forceinline__ float bf2f(unsigned short s) {
  union { unsigned u; float f; } c; c.u = ((unsigned)s) << 16;
  return c.f;
}
__device__ __forceinline__ float dot2(f16x2 a, f16x2 b, float c) {
  return __builtin_amdgcn_fdot2(a, b, c, false);
}
__device__ __forceinline__ void gload16(const void* g, void* l) {
  __builtin_amdgcn_global_load_lds(
      (const __attribute__((address_space(1))) void*)g,
      (__attribute__((address_space(3))) void*)l, 16, 0, 0);
}

// ---------------- Kernel 1: build A = [x_eff | mask | delta] in bf16, [BT, 384]
__global__ void prep_A(const float* __restrict__ X, const float* __restrict__ Xl,
                       const float* __restrict__ Mk, const float* __restrict__ Dl,
                       const float* __restrict__ Xm, const float* __restrict__ Wgx,
                       const float* __restrict__ bgx, unsigned short* __restrict__ A) {
  const int idx = blockIdx.x * 256 + threadIdx.x;   // over BT*D = 8388608
  const int i = idx >> 7;        // row = b*T + t
  const int k = idx & 127;
  const int t = i & (T_ - 1);
  const float d = Dl[idx];
  const float m = Mk[idx];
  const float dx = __expf(-fmaxf(fmaf(d, Wgx[k * 129], bgx[k]), 0.f));  // diag of Wgx
  const float xe = m * X[idx] + (1.f - m) * (dx * Xl[idx] + (1.f - dx) * Xm[t * 128 + k]);
  unsigned short* Ar = A + (size_t)i * 384;
  Ar[k]       = f2bf(xe);
  Ar[128 + k] = f2bf(m);
  Ar[256 + k] = f2bf(d);
}

// ---------------- Kernel 2: build Bt [1024][384] (j-major, bf16) + bias_all[1024]
// j<256: z gate; 256..511: r; 512..767: h; 768..1023: delta_h (Wgh).
// k<128 -> x cols; 128..255 -> m cols (orig 384..511); 256..383 -> delta cols (Wgh).
__global__ void prep_B(const float* __restrict__ Wz, const float* __restrict__ bz,
                       const float* __restrict__ Wr, const float* __restrict__ br,
                       const float* __restrict__ Wh, const float* __restrict__ bh,
                       const float* __restrict__ Wgh, const float* __restrict__ bgh,
                       unsigned short* __restrict__ Bt, float* __restrict__ bias) {
  const int idx = blockIdx.x * 256 + threadIdx.x;   // 1024*384
  if (idx >= 1024 * 384) return;
  const int j = idx / 384;
  const int k = idx - j * 384;
  float v = 0.f;
  if (j < 768) {
    const float* W = (j < 256) ? Wz : (j < 512) ? Wr : Wh;
    const int jj = j & 255;
    if (k < 128) v = W[jj * 512 + k];
    else if (k < 256) v = W[jj * 512 + 384 + (k - 128)];
  } else {
    if (k >= 256) v = Wgh[(j - 768) * 128 + (k - 256)];
  }
  Bt[idx] = f2bf(v);
  if (k == 0)
    bias[j] = (j < 256) ? bz[j] : (j < 512) ? br[j - 256] : (j < 768) ? bh[j - 512] : bgh[j - 768];
}

// ---------------- Kernel 3: GEMM C = A @ Bt^T with fused epilogue
// launch1: jbase=0,  k 0..256   -> pre (bf16, [BT,768], bias added)
// launch2: jbase=768,k 256..384 -> dhb (fp16, [BT,256], exp(-relu(.+bias)))
__global__ __launch_bounds__(256) void gemm_k(
    const unsigned short* __restrict__ A, const unsigned short* __restrict__ Bt,
    const float* __restrict__ bias, unsigned short* __restrict__ pre,
    f16* __restrict__ dhb, int jbase, int kstart, int kend) {
  __shared__ unsigned short As[128 * 64];
  __shared__ unsigned short Bs[128 * 64];
  const int tid = threadIdx.x;
  const int wave = tid >> 6;
  const int lane = tid & 63;
  const int i0 = blockIdx.y * 128;
  const int j0 = jbase + blockIdx.x * 128;
  const int wr = wave >> 1, wc = wave & 1;
  f32x4 acc[4][4] = {};
  for (int kb = kstart; kb < kend; kb += 64) {
    __syncthreads();
#pragma unroll
    for (int it = 0; it < 4; ++it) {
      const int r = wave * 32 + it * 8 + (lane >> 3);
      const int cb = (lane & 7) * 8;
      gload16(A  + (size_t)(i0 + r) * 384 + kb + cb, As + (wave * 32 + it * 8) * 64);
      gload16(Bt + (size_t)(j0 + r) * 384 + kb + cb, Bs + (wave * 32 + it * 8) * 64);
    }
    __syncthreads();
#pragma unroll
    for (int ks = 0; ks < 2; ++ks) {
      bf16x8 af[4], bfr[4];
#pragma unroll
      for (int m = 0; m < 4; ++m) {
        const int row = wr * 64 + m * 16 + (lane & 15);
        af[m] = *(const bf16x8*)(As + row * 64 + ks * 32 + (lane >> 4) * 8);
      }
#pragma unroll
      for (int n = 0; n < 4; ++n) {
        const int col = wc * 64 + n * 16 + (lane & 15);
        bfr[n] = *(const bf16x8*)(Bs + col * 64 + ks * 32 + (lane >> 4) * 8);
      }
#pragma unroll
      for (int m = 0; m < 4; ++m)
#pragma unroll
        for (int n = 0; n < 4; ++n)
          acc[m][n] = __builtin_amdgcn_mfma_f32_16x16x32_bf16(af[m], bfr[n], acc[m][n], 0, 0, 0);
    }
  }
#pragma unroll
  for (int m = 0; m < 4; ++m) {
    const int row0 = i0 + wr * 64 + m * 16 + ((lane >> 4) << 2);
#pragma unroll
    for (int n = 0; n < 4; ++n) {
      const int col = j0 + wc * 64 + n * 16 + (lane & 15);
      const float bv = bias[col];
#pragma unroll
      for (int q = 0; q < 4; ++q) {
        const float v = acc[m][n][q] + bv;
        const size_t r = (size_t)(row0 + q);
        if (jbase < 768) pre[r * 768 + col] = f2bf(v);
        else             dhb[r * 256 + (col - 768)] = (f16)__expf(-fmaxf(v, 0.f));
      }
    }
  }
}

// ---------------- Kernel 4: sequential recurrence, one block per batch row.
// 512 threads: tid<256 -> z-gate row tid (owns h[tid]); tid>=256 -> r-gate row tid-256.
// Phase C: thread (j2=tid&255, khalf=tid>>8) computes half-K partial of h̃ row j2.
// Recurrent weights persistent in registers as fp16 pairs (192 VGPRs/thread).
__global__ __launch_bounds__(512, 2) void grud_seq(
    const float* __restrict__ Wz, const float* __restrict__ Wr, const float* __restrict__ Wh,
    const unsigned short* __restrict__ pre, const f16* __restrict__ dhb,
    float* __restrict__ out, float* __restrict__ out_last) {
  const int b = blockIdx.x;
  const int tid = threadIdx.x;
  const int j2 = tid & 255;
  const int khalf = tid >> 8;
  __shared__ __align__(16) f16 hh[H_];
  __shared__ __align__(16) f16 rhh[H_];
  __shared__ float scr[H_];

  f16x2 w1[128];  // Wz_h row (tid<256) or Wr_h row (tid>=256), all K=256
  {
    const float* Wg = (tid < 256) ? Wz : Wr;
#pragma unroll
    for (int kk = 0; kk < 128; ++kk) {
      float2 wv = *(const float2*)(Wg + j2 * 512 + 128 + kk * 2);
      w1[kk].x = (f16)wv.x; w1[kk].y = (f16)wv.y;
    }
  }
  f16x2 w2[64];   // Wh_h row j2, half-K (khalf selects 128 of 256)
#pragma unroll
  for (int kk = 0; kk < 64; ++kk) {
    float2 wv = *(const float2*)(Wh + j2 * 512 + 128 + khalf * 128 + kk * 2);
    w2[kk].x = (f16)wv.x; w2[kk].y = (f16)wv.y;
  }

  float hreg = 0.f, zreg = 0.f, h1reg = 0.f;
  const size_t rowbase = (size_t)b * T_;
  float* outb = out + (size_t)b * T_ * H_;

  for (int t = 0; t < T_; ++t) {
    const size_t rowi = rowbase + t;
    const unsigned short* prow = pre + rowi * 768;
    // A: decay h
    if (tid < 256) {
      float dv = (float)dhb[rowi * 256 + tid];
      h1reg = dv * hreg;
      hh[tid] = (f16)h1reg;
    }
    __syncthreads();
    // B: z and r gates (full-K dot per thread)
    float g0 = 0, g1 = 0, g2 = 0, g3 = 0;
    {
      const uint4* hv = (const uint4*)hh;
#pragma unroll
      for (int q = 0; q < 32; ++q) {
        uint4 hw = hv[q];
        g0 = dot2(w1[4 * q + 0], __builtin_bit_cast(f16x2, hw.x), g0);
        g1 = dot2(w1[4 * q + 1], __builtin_bit_cast(f16x2, hw.y), g1);
        g2 = dot2(w1[4 * q + 2], __builtin_bit_cast(f16x2, hw.z), g2);
        g3 = dot2(w1[4 * q + 3], __builtin_bit_cast(f16x2, hw.w), g3);
      }
    }
    {
      float a = bf2f(prow[tid]) + ((g0 + g1) + (g2 + g3));
      float gate = 1.f / (1.f + __expf(-a));
      if (tid < 256) {
        zreg = gate;
      } else {
        float h1f = (float)hh[j2];
        rhh[j2] = (f16)(gate * h1f);
      }
    }
    __syncthreads();
    // C: h̃ half-K partials
    float c0 = 0, c1 = 0, c2 = 0, c3 = 0;
    {
      const uint4* rv = (const uint4*)rhh;
#pragma unroll
      for (int q = 0; q < 16; ++q) {
        uint4 rw = rv[khalf * 16 + q];
        c0 = dot2(w2[4 * q + 0], __builtin_bit_cast(f16x2, rw.x), c0);
        c1 = dot2(w2[4 * q + 1], __builtin_bit_cast(f16x2, rw.y), c1);
        c2 = dot2(w2[4 * q + 2], __builtin_bit_cast(f16x2, rw.z), c2);
        c3 = dot2(w2[4 * q + 3], __builtin_bit_cast(f16x2, rw.w), c3);
      }
    }
    float csum = (c0 + c1) + (c2 + c3);
    if (khalf) scr[j2] = csum;
    __syncthreads();
    // D: combine, update h, write out
    if (tid < 256) {
      float tot = bf2f(prow[512 + tid]) + csum + scr[tid];
      float e = __expf(-2.f * tot);
      float htil = (1.f - e) / (1.f + e);   // tanh
      float hn = (1.f - zreg) * h1reg + zreg * htil;
      outb[t * H_ + tid] = hn;
      hreg = hn;
    }
  }
  if (tid < 256) out_last[(size_t)b * H_ + tid] = hreg;
}

extern "C" void kernel_launch(void* const* d_in, const int* in_sizes, int n_in,
                              void* d_out, int out_size, void* d_ws, size_t ws_size,
                              hipStream_t stream) {
  const float* X   = (const float*)d_in[0];
  const float* Xl  = (const float*)d_in[1];
  const float* Mk  = (const float*)d_in[2];
  const float* Dl  = (const float*)d_in[3];
  const float* Xm  = (const float*)d_in[4];
  const float* Wz  = (const float*)d_in[5];
  const float* bz  = (const float*)d_in[6];
  const float* Wr  = (const float*)d_in[7];
  const float* br  = (const float*)d_in[8];
  const float* Wh  = (const float*)d_in[9];
  const float* bh  = (const float*)d_in[10];
  const float* Wgx = (const float*)d_in[11];
  const float* bgx = (const float*)d_in[12];
  const float* Wgh = (const float*)d_in[13];
  const float* bgh = (const float*)d_in[14];

  char* ws = (char*)d_ws;
  unsigned short* A    = (unsigned short*)(ws);                 // 65536*384*2  = 50331648
  unsigned short* Bt   = (unsigned short*)(ws + 50331648);      // 1024*384*2   = 786432
  float*          bias = (float*)(ws + 51118080);               // 1024*4       = 4096
  unsigned short* pre  = (unsigned short*)(ws + 51122176);      // 65536*768*2  = 100663296
  f16*            dhb  = (f16*)(ws + 151785472);                // 65536*256*2  = 33554432

  float* out = (float*)d_out;
  float* out_last = out + (size_t)B_ * T_ * H_;

  prep_A<<<dim3(32768), dim3(256), 0, stream>>>(X, Xl, Mk, Dl, Xm, Wgx, bgx, A);
  prep_B<<<dim3(1536), dim3(256), 0, stream>>>(Wz, bz, Wr, br, Wh, bh, Wgh, bgh, Bt, bias);
  gemm_k<<<dim3(6, 512), dim3(256), 0, stream>>>(A, Bt, bias, pre, dhb, 0, 0, 256);
  gemm_k<<<dim3(2, 512), dim3(256), 0, stream>>>(A, Bt, bias, pre, dhb, 768, 256, 384);
  grud_seq<<<dim3(256), dim3(512), 0, stream>>>(Wz, Wr, Wh, pre, dhb, out, out_last);
}